// Round 5
// baseline (96.887 us; speedup 1.0000x reference)
//
#include <hip/hip_runtime.h>
#include <math.h>

#define NTOK 8192
#define DIMV 512
#define CD 13
#define KSZ 8192
#define NPARTS 512            /* KA block count == partial-C count          */
#define TPB 16                /* tokens per KA block                        */

/* d_ws layout (ws_size = 256 MB confirmed by poison-fill WRITE_SIZE):
   [0, 16MB)      ws_C   : NPARTS x 8192 partial C
   [+0, +4KB)     ws_pc  : 512 x {cm, pe}
   [+4KB, +256B)  ws_e   : 64 entropy partials                              */
#define C_BYTES  ((size_t)NPARTS * KSZ * 4)
#define PC_OFF   C_BYTES
#define E_OFF    (PC_OFF + 4096)

// ---------------------------------------------------------------------------
// KA: fused h-projection + indices + commit/per-sample-entropy partials +
//     out = sign(h) @ w_out + b_out + 16-token partial avg_probs C.
// 16 lanes per token, 4 tokens per wave, 16 tokens per block, 512 blocks.
// ---------------------------------------------------------------------------
__global__ __launch_bounds__(256) void ka_fused(const float* __restrict__ x,
                                                const float* __restrict__ w_in,
                                                const float* __restrict__ b_in,
                                                const float* __restrict__ w_out,
                                                const float* __restrict__ b_out,
                                                float* __restrict__ ws_C,
                                                float* __restrict__ ws_pc,
                                                float* __restrict__ outv,
                                                float* __restrict__ out_ind) {
  __shared__ __align__(16) float s_winT[CD * DIMV];  // [c][d], transposed
  __shared__ __align__(16) float s_wout[CD * DIMV];  // [c][d], native layout
  __shared__ float sh[TPB][CD];                      // h per token
  __shared__ __align__(16) float sA[TPB][2][32];     // [tok][khi&1][khi>>1]
  __shared__ __align__(16) float sB[TPB][128];       // [tok][klo]
  __shared__ float s_cm[16], s_pe[16];
  int t = threadIdx.x;

  // stage weights; conflict-free LDS writes (bank = (c*512+d)%32 = d%32,
  // d == t mod 256 -> 2 lanes/bank)
  for (int d = t; d < DIMV; d += 256) {
#pragma unroll
    for (int c = 0; c < CD; ++c) s_winT[c * DIMV + d] = w_in[d * CD + c];
  }
  for (int g = t; g < CD * DIMV; g += 256) s_wout[g] = w_out[g];
  __syncthreads();

  int lane = t & 63;
  int wave = t >> 6;
  int l15 = lane & 15;
  int grp = lane >> 4;
  int tok = wave * 4 + grp;
  int n = blockIdx.x * TPB + tok;

  const float4* x4 = (const float4*)(x + (size_t)n * DIMV);

  // per-lane f32 partial over 32 elements of d
  float facc[CD];
#pragma unroll
  for (int c = 0; c < CD; ++c) facc[c] = 0.f;
#pragma unroll
  for (int j = 0; j < 8; ++j) {
    float4 xv = x4[l15 + j * 16];
    int dbase = (l15 + j * 16) * 4;
#pragma unroll
    for (int c = 0; c < CD; ++c) {
      const float4 wv = *(const float4*)&s_winT[c * DIMV + dbase];
      facc[c] += xv.x * wv.x + xv.y * wv.y + xv.z * wv.z + xv.w * wv.w;
    }
  }
  // f64 butterfly across the 16-lane group; every lane ends with all 13 h's
  double acc[CD];
#pragma unroll
  for (int c = 0; c < CD; ++c) {
    double a = (double)facc[c];
    a += __shfl_xor(a, 1, 64);
    a += __shfl_xor(a, 2, 64);
    a += __shfl_xor(a, 4, 64);
    a += __shfl_xor(a, 8, 64);
    acc[c] = a + (double)b_in[c];
  }

  // index
  int idx = 0;
#pragma unroll
  for (int c = 0; c < CD; ++c) idx |= (acc[c] > 0.0 ? 1 : 0) << (12 - c);
  if (l15 == 0) out_ind[n] = (float)idx;

  // lane l15 owns channel c==l15: h -> LDS, commit + entropy partials
  float hv = 0.f;
#pragma unroll
  for (int c = 0; c < CD; ++c) if (l15 == c) hv = (float)acc[c];
  float cm = 0.f, pe = 0.f;
  if (l15 < CD) {
    sh[tok][l15] = hv;
    float a = fabsf(hv);
    float d1 = a - 1.f;
    cm = d1 * d1;                       // (h - sign(h))^2 == (|h|-1)^2
    float z = 4.f * a;                  // binary entropy of sigmoid(4h)
    float e = expf(-z);
    pe = log1pf(e) + z * e / (1.f + e);
  }
  cm += __shfl_xor(cm, 1, 64); pe += __shfl_xor(pe, 1, 64);
  cm += __shfl_xor(cm, 2, 64); pe += __shfl_xor(pe, 2, 64);
  cm += __shfl_xor(cm, 4, 64); pe += __shfl_xor(pe, 4, 64);
  cm += __shfl_xor(cm, 8, 64); pe += __shfl_xor(pe, 8, 64);
  if (l15 == 0) { s_cm[tok] = cm; s_pe[tok] = pe; }

  // out = sign(h) @ w_out + b_out; c-outer so each w_out float4 serves 4 tokens
  int dpos = lane * 4;
  int id2[4];
#pragma unroll
  for (int tt = 0; tt < 4; ++tt) id2[tt] = __shfl(idx, tt * 16, 64);
  float4 o[4][2];
  {
    float4 bo0 = *(const float4*)(b_out + dpos);
    float4 bo1 = *(const float4*)(b_out + dpos + 256);
#pragma unroll
    for (int tt = 0; tt < 4; ++tt) { o[tt][0] = bo0; o[tt][1] = bo1; }
  }
#pragma unroll
  for (int c = 0; c < CD; ++c) {
    const float4 w0 = *(const float4*)&s_wout[c * DIMV + dpos];
    const float4 w1 = *(const float4*)&s_wout[c * DIMV + dpos + 256];
#pragma unroll
    for (int tt = 0; tt < 4; ++tt) {
      float sgn = ((id2[tt] >> (12 - c)) & 1) ? 1.f : -1.f;
      o[tt][0].x = fmaf(sgn, w0.x, o[tt][0].x);
      o[tt][0].y = fmaf(sgn, w0.y, o[tt][0].y);
      o[tt][0].z = fmaf(sgn, w0.z, o[tt][0].z);
      o[tt][0].w = fmaf(sgn, w0.w, o[tt][0].w);
      o[tt][1].x = fmaf(sgn, w1.x, o[tt][1].x);
      o[tt][1].y = fmaf(sgn, w1.y, o[tt][1].y);
      o[tt][1].z = fmaf(sgn, w1.z, o[tt][1].z);
      o[tt][1].w = fmaf(sgn, w1.w, o[tt][1].w);
    }
  }
  int n0 = blockIdx.x * TPB + wave * 4;
#pragma unroll
  for (int tt = 0; tt < 4; ++tt) {
    float4* dst = (float4*)(outv + (size_t)(n0 + tt) * DIMV);
    dst[lane] = o[tt][0];
    dst[lane + 64] = o[tt][1];
  }

  __syncthreads();                       // sh + s_cm/s_pe complete

  if (t == 0) {
    float C = 0.f, P = 0.f;
#pragma unroll
    for (int i = 0; i < 16; ++i) { C += s_cm[i]; P += s_pe[i]; }
    ws_pc[blockIdx.x * 2] = C;
    ws_pc[blockIdx.x * 2 + 1] = P;
  }

  // ---- phase 1: per-token factor vectors A[64], B[128] (wave m%4) ----
  for (int m = wave; m < TPB; m += 4) {
    float p[CD], q[CD];
#pragma unroll
    for (int c = 0; c < CD; ++c) {
      float hvv = sh[m][c];             // LDS broadcast
      float e = expf(-4.f * hvv);
      float r = 1.f / (1.f + e);
      p[c] = r;                         // P(bit c = 1)
      q[c] = e * r;                     // P(bit c = 0)
    }
    float A = ((lane >> 5) & 1) ? p[0] : q[0];
    A *= ((lane >> 4) & 1) ? p[1] : q[1];
    A *= ((lane >> 3) & 1) ? p[2] : q[2];
    A *= ((lane >> 2) & 1) ? p[3] : q[3];
    A *= ((lane >> 1) & 1) ? p[4] : q[4];
    A *= (lane & 1) ? p[5] : q[5];
    sA[m][lane & 1][lane >> 1] = A;
    float Bb = ((lane >> 5) & 1) ? p[7] : q[7];
    Bb *= ((lane >> 4) & 1) ? p[8] : q[8];
    Bb *= ((lane >> 3) & 1) ? p[9] : q[9];
    Bb *= ((lane >> 2) & 1) ? p[10] : q[10];
    Bb *= ((lane >> 1) & 1) ? p[11] : q[11];
    Bb *= (lane & 1) ? p[12] : q[12];
    sB[m][lane] = q[6] * Bb;            // klo = lane      (bit6 = 0)
    sB[m][64 + lane] = p[6] * Bb;       // klo = lane + 64 (bit6 = 1)
  }
  __syncthreads();

  // ---- phase 2: thread t owns slots s = t + 256*j; khi = 2j+c2, klo=t&127 --
  int c2 = t >> 7;
  int klo = t & 127;
  float acc2[32];
#pragma unroll
  for (int j = 0; j < 32; ++j) acc2[j] = 0.f;
  for (int m = 0; m < TPB; ++m) {
    float Bv = sB[m][klo];
    const float4* A4 = (const float4*)&sA[m][c2][0];  // uniform (broadcast)
#pragma unroll
    for (int jj = 0; jj < 8; ++jj) {
      float4 a = A4[jj];
      acc2[jj * 4 + 0] = fmaf(a.x, Bv, acc2[jj * 4 + 0]);
      acc2[jj * 4 + 1] = fmaf(a.y, Bv, acc2[jj * 4 + 1]);
      acc2[jj * 4 + 2] = fmaf(a.z, Bv, acc2[jj * 4 + 2]);
      acc2[jj * 4 + 3] = fmaf(a.w, Bv, acc2[jj * 4 + 3]);
    }
  }
  float* dst = ws_C + (size_t)blockIdx.x * KSZ;
#pragma unroll
  for (int j = 0; j < 32; ++j) dst[t + 256 * j] = acc2[j];  // coalesced
}

// ---------------------------------------------------------------------------
// KB: reduce NPARTS partial C's -> 64 per-block entropy partials.
// 64 blocks x 128 slots; 2 part-groups per thread.
// ---------------------------------------------------------------------------
__global__ __launch_bounds__(256) void kb_cbent(const float* __restrict__ ws_C,
                                                float* __restrict__ ws_e) {
  __shared__ float red[256];
  __shared__ float s2[2];
  int t = threadIdx.x;
  int s = blockIdx.x * 128 + (t & 127);
  int pg = t >> 7;
  float sum = 0.f;
  for (int p = pg; p < NPARTS; p += 2) sum += ws_C[(size_t)p * KSZ + s];
  red[t] = sum;
  __syncthreads();
  float contrib = 0.f;
  if (t < 128) {
    float v = red[t] + red[t + 128];
    float avg = v * (1.f / (float)NTOK);
    contrib = -avg * logf(avg + 1e-5f);
  }
  contrib += __shfl_xor(contrib, 1, 64);
  contrib += __shfl_xor(contrib, 2, 64);
  contrib += __shfl_xor(contrib, 4, 64);
  contrib += __shfl_xor(contrib, 8, 64);
  contrib += __shfl_xor(contrib, 16, 64);
  contrib += __shfl_xor(contrib, 32, 64);
  if ((t & 63) == 0 && t < 128) s2[t >> 6] = contrib;
  __syncthreads();
  if (t == 0) ws_e[blockIdx.x] = s2[0] + s2[1];
}

// ---------------------------------------------------------------------------
// KC: final assembly (single block, fixed-order deterministic sums).
// ---------------------------------------------------------------------------
__global__ __launch_bounds__(256) void kc_final(const float* __restrict__ ws_pc,
                                                const float* __restrict__ ws_e,
                                                float* __restrict__ d_aux) {
  __shared__ float rc[256], rp[256], re[256];
  int t = threadIdx.x;
  float cm = 0.f, pe = 0.f;
  for (int i = t; i < 512; i += 256) { cm += ws_pc[2 * i]; pe += ws_pc[2 * i + 1]; }
  rc[t] = cm; rp[t] = pe; re[t] = (t < 64) ? ws_e[t] : 0.f;
  __syncthreads();
  if (t < 64) {
    float C = rc[t] + rc[t + 64] + rc[t + 128] + rc[t + 192];
    float P = rp[t] + rp[t + 64] + rp[t + 128] + rp[t + 192];
    float E = re[t];
    C += __shfl_xor(C, 1, 64); P += __shfl_xor(P, 1, 64); E += __shfl_xor(E, 1, 64);
    C += __shfl_xor(C, 2, 64); P += __shfl_xor(P, 2, 64); E += __shfl_xor(E, 2, 64);
    C += __shfl_xor(C, 4, 64); P += __shfl_xor(P, 4, 64); E += __shfl_xor(E, 4, 64);
    C += __shfl_xor(C, 8, 64); P += __shfl_xor(P, 8, 64); E += __shfl_xor(E, 8, 64);
    C += __shfl_xor(C, 16, 64); P += __shfl_xor(P, 16, 64); E += __shfl_xor(E, 16, 64);
    C += __shfl_xor(C, 32, 64); P += __shfl_xor(P, 32, 64); E += __shfl_xor(E, 32, 64);
    if (t == 0) {
      float commit = C * (1.f / (float)(NTOK * CD));
      float psE = P * (1.f / (float)NTOK);
      d_aux[0] = 0.1f * (psE - E) + 0.25f * commit;
    }
  }
}

extern "C" void kernel_launch(void* const* d_in, const int* in_sizes, int n_in,
                              void* d_out, int out_size, void* d_ws, size_t ws_size,
                              hipStream_t stream) {
  const float* x     = (const float*)d_in[0];
  const float* w_in  = (const float*)d_in[1];
  const float* b_in  = (const float*)d_in[2];
  const float* w_out = (const float*)d_in[3];
  const float* b_out = (const float*)d_in[4];
  // d_in[5] = codebook (unused: codes are the 13-bit sign patterns)

  float* outv = (float*)d_out;                       // [4*2048*512]
  float* ind  = outv + (size_t)NTOK * DIMV;          // [8192] as float
  float* aux  = ind + NTOK;                          // [1]

  float* ws_C  = (float*)d_ws;
  float* ws_pc = (float*)((char*)d_ws + PC_OFF);
  float* ws_e  = (float*)((char*)d_ws + E_OFF);

  ka_fused<<<NTOK / TPB, 256, 0, stream>>>(x, w_in, b_in, w_out, b_out,
                                           ws_C, ws_pc, outv, ind);
  kb_cbent<<<64, 256, 0, stream>>>(ws_C, ws_e);
  kc_final<<<1, 256, 0, stream>>>(ws_pc, ws_e, aux);
}

// Round 6
// 40.977 us; speedup vs baseline: 2.3644x; 2.3644x over previous
//
#include <hip/hip_runtime.h>
#include <math.h>

#define NTOK 8192
#define DIMV 512
#define CD 13
#define KSZ 8192
#define NPARTS 512            /* KA block count == partial-C count          */
#define TPB 16                /* tokens per KA block                        */

/* d_ws layout:
   [0, 16MB)        ws_C  : NPARTS x 8192 partial C
   [+0, +4KB)       ws_pc : 512 x {cm, pe}
   [+4KB, +1KB)     ws_e  : 256 entropy partials                            */
#define C_BYTES  ((size_t)NPARTS * KSZ * 4)
#define PC_OFF   C_BYTES
#define E_OFF    (PC_OFF + 4096)

// ---------------------------------------------------------------------------
// KA: fused h-projection + indices + commit/per-sample-entropy partials +
//     out = sign(h) @ w_out + b_out + 16-token partial avg_probs C.
// 16 lanes per token, 4 tokens per wave, 16 tokens per block, 512 blocks.
// w_out is read from global (L2-resident 26 KB) to keep LDS under 40 KB
// -> 4 blocks/CU.
// ---------------------------------------------------------------------------
__global__ __launch_bounds__(256) void ka_fused(const float* __restrict__ x,
                                                const float* __restrict__ w_in,
                                                const float* __restrict__ b_in,
                                                const float* __restrict__ w_out,
                                                const float* __restrict__ b_out,
                                                float* __restrict__ ws_C,
                                                float* __restrict__ ws_pc,
                                                float* __restrict__ outv,
                                                float* __restrict__ out_ind) {
  __shared__ __align__(16) float s_winT[CD * DIMV];  // [c][d], transposed
  __shared__ float sh[TPB][CD];                      // h per token
  __shared__ __align__(16) float sA[TPB][2][32];     // [tok][khi&1][khi>>1]
  __shared__ __align__(16) float sB[TPB][128];       // [tok][klo]
  __shared__ float s_cm[16], s_pe[16];
  int t = threadIdx.x;

  for (int d = t; d < DIMV; d += 256) {
#pragma unroll
    for (int c = 0; c < CD; ++c) s_winT[c * DIMV + d] = w_in[d * CD + c];
  }
  __syncthreads();

  int lane = t & 63;
  int wave = t >> 6;
  int l15 = lane & 15;
  int grp = lane >> 4;
  int tok = wave * 4 + grp;
  int n = blockIdx.x * TPB + tok;

  const float4* x4 = (const float4*)(x + (size_t)n * DIMV);

  // per-lane f32 partial over 32 elements of d
  float facc[CD];
#pragma unroll
  for (int c = 0; c < CD; ++c) facc[c] = 0.f;
#pragma unroll
  for (int j = 0; j < 8; ++j) {
    float4 xv = x4[l15 + j * 16];
    int dbase = (l15 + j * 16) * 4;
#pragma unroll
    for (int c = 0; c < CD; ++c) {
      const float4 wv = *(const float4*)&s_winT[c * DIMV + dbase];
      facc[c] += xv.x * wv.x + xv.y * wv.y + xv.z * wv.z + xv.w * wv.w;
    }
  }
  // f64 butterfly across the 16-lane group; every lane ends with all 13 h's
  double acc[CD];
#pragma unroll
  for (int c = 0; c < CD; ++c) {
    double a = (double)facc[c];
    a += __shfl_xor(a, 1, 64);
    a += __shfl_xor(a, 2, 64);
    a += __shfl_xor(a, 4, 64);
    a += __shfl_xor(a, 8, 64);
    acc[c] = a + (double)b_in[c];
  }

  // index
  int idx = 0;
#pragma unroll
  for (int c = 0; c < CD; ++c) idx |= (acc[c] > 0.0 ? 1 : 0) << (12 - c);
  if (l15 == 0) out_ind[n] = (float)idx;

  // lane l15 owns channel c==l15: h -> LDS, commit + entropy partials
  float hv = 0.f;
#pragma unroll
  for (int c = 0; c < CD; ++c) if (l15 == c) hv = (float)acc[c];
  float cm = 0.f, pe = 0.f;
  if (l15 < CD) {
    sh[tok][l15] = hv;
    float a = fabsf(hv);
    float d1 = a - 1.f;
    cm = d1 * d1;                       // (h - sign(h))^2 == (|h|-1)^2
    float z = 4.f * a;                  // binary entropy of sigmoid(4h)
    float e = expf(-z);
    pe = log1pf(e) + z * e / (1.f + e);
  }
  cm += __shfl_xor(cm, 1, 64); pe += __shfl_xor(pe, 1, 64);
  cm += __shfl_xor(cm, 2, 64); pe += __shfl_xor(pe, 2, 64);
  cm += __shfl_xor(cm, 4, 64); pe += __shfl_xor(pe, 4, 64);
  cm += __shfl_xor(cm, 8, 64); pe += __shfl_xor(pe, 8, 64);
  if (l15 == 0) { s_cm[tok] = cm; s_pe[tok] = pe; }

  // out = sign(h) @ w_out + b_out; c-outer, w_out float4 from L2 serves 4 toks
  int dpos = lane * 4;
  int id2[4];
#pragma unroll
  for (int tt = 0; tt < 4; ++tt) id2[tt] = __shfl(idx, tt * 16, 64);
  float4 o[4][2];
  {
    float4 bo0 = *(const float4*)(b_out + dpos);
    float4 bo1 = *(const float4*)(b_out + dpos + 256);
#pragma unroll
    for (int tt = 0; tt < 4; ++tt) { o[tt][0] = bo0; o[tt][1] = bo1; }
  }
#pragma unroll
  for (int c = 0; c < CD; ++c) {
    const float4 w0 = *(const float4*)&w_out[c * DIMV + dpos];
    const float4 w1 = *(const float4*)&w_out[c * DIMV + dpos + 256];
#pragma unroll
    for (int tt = 0; tt < 4; ++tt) {
      float sgn = ((id2[tt] >> (12 - c)) & 1) ? 1.f : -1.f;
      o[tt][0].x = fmaf(sgn, w0.x, o[tt][0].x);
      o[tt][0].y = fmaf(sgn, w0.y, o[tt][0].y);
      o[tt][0].z = fmaf(sgn, w0.z, o[tt][0].z);
      o[tt][0].w = fmaf(sgn, w0.w, o[tt][0].w);
      o[tt][1].x = fmaf(sgn, w1.x, o[tt][1].x);
      o[tt][1].y = fmaf(sgn, w1.y, o[tt][1].y);
      o[tt][1].z = fmaf(sgn, w1.z, o[tt][1].z);
      o[tt][1].w = fmaf(sgn, w1.w, o[tt][1].w);
    }
  }
  int n0 = blockIdx.x * TPB + wave * 4;
#pragma unroll
  for (int tt = 0; tt < 4; ++tt) {
    float4* dst = (float4*)(outv + (size_t)(n0 + tt) * DIMV);
    dst[lane] = o[tt][0];
    dst[lane + 64] = o[tt][1];
  }

  __syncthreads();                       // sh + s_cm/s_pe complete

  if (t == 0) {
    float C = 0.f, P = 0.f;
#pragma unroll
    for (int i = 0; i < 16; ++i) { C += s_cm[i]; P += s_pe[i]; }
    ws_pc[blockIdx.x * 2] = C;
    ws_pc[blockIdx.x * 2 + 1] = P;
  }

  // ---- phase 1: per-token factor vectors A[64], B[128] (wave m%4) ----
  for (int m = wave; m < TPB; m += 4) {
    float p[CD], q[CD];
#pragma unroll
    for (int c = 0; c < CD; ++c) {
      float hvv = sh[m][c];             // LDS broadcast
      float e = expf(-4.f * hvv);
      float r = 1.f / (1.f + e);
      p[c] = r;                         // P(bit c = 1)
      q[c] = e * r;                     // P(bit c = 0)
    }
    float A = ((lane >> 5) & 1) ? p[0] : q[0];
    A *= ((lane >> 4) & 1) ? p[1] : q[1];
    A *= ((lane >> 3) & 1) ? p[2] : q[2];
    A *= ((lane >> 2) & 1) ? p[3] : q[3];
    A *= ((lane >> 1) & 1) ? p[4] : q[4];
    A *= (lane & 1) ? p[5] : q[5];
    sA[m][lane & 1][lane >> 1] = A;
    float Bb = ((lane >> 5) & 1) ? p[7] : q[7];
    Bb *= ((lane >> 4) & 1) ? p[8] : q[8];
    Bb *= ((lane >> 3) & 1) ? p[9] : q[9];
    Bb *= ((lane >> 2) & 1) ? p[10] : q[10];
    Bb *= ((lane >> 1) & 1) ? p[11] : q[11];
    Bb *= (lane & 1) ? p[12] : q[12];
    sB[m][lane] = q[6] * Bb;            // klo = lane      (bit6 = 0)
    sB[m][64 + lane] = p[6] * Bb;       // klo = lane + 64 (bit6 = 1)
  }
  __syncthreads();

  // ---- phase 2: thread t owns slots s = t + 256*j; khi = 2j+c2, klo=t&127 --
  int c2 = t >> 7;
  int klo = t & 127;
  float acc2[32];
#pragma unroll
  for (int j = 0; j < 32; ++j) acc2[j] = 0.f;
  for (int m = 0; m < TPB; ++m) {
    float Bv = sB[m][klo];
    const float4* A4 = (const float4*)&sA[m][c2][0];  // uniform (broadcast)
#pragma unroll
    for (int jj = 0; jj < 8; ++jj) {
      float4 a = A4[jj];
      acc2[jj * 4 + 0] = fmaf(a.x, Bv, acc2[jj * 4 + 0]);
      acc2[jj * 4 + 1] = fmaf(a.y, Bv, acc2[jj * 4 + 1]);
      acc2[jj * 4 + 2] = fmaf(a.z, Bv, acc2[jj * 4 + 2]);
      acc2[jj * 4 + 3] = fmaf(a.w, Bv, acc2[jj * 4 + 3]);
    }
  }
  float* dst = ws_C + (size_t)blockIdx.x * KSZ;
#pragma unroll
  for (int j = 0; j < 32; ++j) dst[t + 256 * j] = acc2[j];  // coalesced
}

// ---------------------------------------------------------------------------
// KB: reduce NPARTS partial C's -> 256 per-block entropy partials.
// 256 blocks x 32 slots; 8 part-groups/thread, 64 loads with 4-way ILP.
// ---------------------------------------------------------------------------
__global__ __launch_bounds__(256) void kb_cbent(const float* __restrict__ ws_C,
                                                float* __restrict__ ws_e) {
  __shared__ float red[256];
  int t = threadIdx.x;
  int sl = t & 31, pg = t >> 5;
  int s = blockIdx.x * 32 + sl;
  float a0 = 0.f, a1 = 0.f, a2 = 0.f, a3 = 0.f;
  // p = pg + 8*i, i in [0,64); unroll 4 with independent accumulators
  for (int i = 0; i < 64; i += 4) {
    a0 += ws_C[(size_t)(pg + 8 * (i + 0)) * KSZ + s];
    a1 += ws_C[(size_t)(pg + 8 * (i + 1)) * KSZ + s];
    a2 += ws_C[(size_t)(pg + 8 * (i + 2)) * KSZ + s];
    a3 += ws_C[(size_t)(pg + 8 * (i + 3)) * KSZ + s];
  }
  red[t] = (a0 + a1) + (a2 + a3);
  __syncthreads();
  float contrib = 0.f;
  if (t < 32) {
    float v = red[t];
#pragma unroll
    for (int j = 1; j < 8; ++j) v += red[t + 32 * j];
    float avg = v * (1.f / (float)NTOK);
    contrib = -avg * logf(avg + 1e-5f);
  }
  if (t < 64) {
    contrib += __shfl_xor(contrib, 1, 64);
    contrib += __shfl_xor(contrib, 2, 64);
    contrib += __shfl_xor(contrib, 4, 64);
    contrib += __shfl_xor(contrib, 8, 64);
    contrib += __shfl_xor(contrib, 16, 64);
    if (t == 0) ws_e[blockIdx.x] = contrib;
  }
}

// ---------------------------------------------------------------------------
// KC: final assembly (single block, fixed-order deterministic sums).
// ---------------------------------------------------------------------------
__global__ __launch_bounds__(256) void kc_final(const float* __restrict__ ws_pc,
                                                const float* __restrict__ ws_e,
                                                float* __restrict__ d_aux) {
  __shared__ float rc[256], rp[256], re[256];
  int t = threadIdx.x;
  float cm = 0.f, pe = 0.f;
  for (int i = t; i < 512; i += 256) { cm += ws_pc[2 * i]; pe += ws_pc[2 * i + 1]; }
  rc[t] = cm; rp[t] = pe; re[t] = ws_e[t];
  __syncthreads();
  if (t < 64) {
    float C = rc[t] + rc[t + 64] + rc[t + 128] + rc[t + 192];
    float P = rp[t] + rp[t + 64] + rp[t + 128] + rp[t + 192];
    float E = re[t] + re[t + 64] + re[t + 128] + re[t + 192];
    C += __shfl_xor(C, 1, 64); P += __shfl_xor(P, 1, 64); E += __shfl_xor(E, 1, 64);
    C += __shfl_xor(C, 2, 64); P += __shfl_xor(P, 2, 64); E += __shfl_xor(E, 2, 64);
    C += __shfl_xor(C, 4, 64); P += __shfl_xor(P, 4, 64); E += __shfl_xor(E, 4, 64);
    C += __shfl_xor(C, 8, 64); P += __shfl_xor(P, 8, 64); E += __shfl_xor(E, 8, 64);
    C += __shfl_xor(C, 16, 64); P += __shfl_xor(P, 16, 64); E += __shfl_xor(E, 16, 64);
    C += __shfl_xor(C, 32, 64); P += __shfl_xor(P, 32, 64); E += __shfl_xor(E, 32, 64);
    if (t == 0) {
      float commit = C * (1.f / (float)(NTOK * CD));
      float psE = P * (1.f / (float)NTOK);
      d_aux[0] = 0.1f * (psE - E) + 0.25f * commit;
    }
  }
}

extern "C" void kernel_launch(void* const* d_in, const int* in_sizes, int n_in,
                              void* d_out, int out_size, void* d_ws, size_t ws_size,
                              hipStream_t stream) {
  const float* x     = (const float*)d_in[0];
  const float* w_in  = (const float*)d_in[1];
  const float* b_in  = (const float*)d_in[2];
  const float* w_out = (const float*)d_in[3];
  const float* b_out = (const float*)d_in[4];
  // d_in[5] = codebook (unused: codes are the 13-bit sign patterns)

  float* outv = (float*)d_out;                       // [4*2048*512]
  float* ind  = outv + (size_t)NTOK * DIMV;          // [8192] as float
  float* aux  = ind + NTOK;                          // [1]

  float* ws_C  = (float*)d_ws;
  float* ws_pc = (float*)((char*)d_ws + PC_OFF);
  float* ws_e  = (float*)((char*)d_ws + E_OFF);

  ka_fused<<<NTOK / TPB, 256, 0, stream>>>(x, w_in, b_in, w_out, b_out,
                                           ws_C, ws_pc, outv, ind);
  kb_cbent<<<256, 256, 0, stream>>>(ws_C, ws_e);
  kc_final<<<1, 256, 0, stream>>>(ws_pc, ws_e, aux);
}